// Round 4
// baseline (1914.027 us; speedup 1.0000x reference)
//
#include <hip/hip_runtime.h>

#define CH 32        // events per chunk
#define NCHUNK 32    // 1024 / CH
#define NE 1024
#define DH 400
#define DIN 784

// TAU = -1/ln(0.2) as the reference's Python double, rounded to f32 (JAX weak-type promotion)
#define TAUF ((float)0.6213349345596119)

// -------- prep: transpose W1 [400,784] -> W1T [784,400] in workspace (+64 zero pad) --------
__global__ void prep_transpose(const float* __restrict__ W1, float* __restrict__ W1T) {
  int idx = blockIdx.x * 256 + threadIdx.x;
  const int total = DIN * DH;
  if (idx < total) {
    int p = idx / DH;
    int j = idx - p * DH;
    W1T[idx] = W1[j * DIN + p];
  } else if (idx < total + 64) {
    W1T[idx] = 0.0f;  // pad so producer threads 400..447 stay in-bounds
  }
}

__device__ __forceinline__ unsigned long long rfl64(unsigned long long x) {
  unsigned int lo = __builtin_amdgcn_readfirstlane((unsigned int)(x & 0xffffffffull));
  unsigned int hi = __builtin_amdgcn_readfirstlane((unsigned int)(x >> 32));
  return (((unsigned long long)hi) << 32) | (unsigned long long)lo;
}

// extract next fired neuron index in ascending j order; 400 = dummy (zero weight row)
#define NEXTJ(JV)                                              \
  do {                                                         \
    if (q0)      { JV = __builtin_ctzll(q0);       q0 &= q0 - 1; } \
    else if (q1) { JV = 64 + __builtin_ctzll(q1);  q1 &= q1 - 1; } \
    else if (q2) { JV = 128 + __builtin_ctzll(q2); q2 &= q2 - 1; } \
    else if (q3) { JV = 192 + __builtin_ctzll(q3); q3 &= q3 - 1; } \
    else if (q4) { JV = 256 + __builtin_ctzll(q4); q4 &= q4 - 1; } \
    else if (q5) { JV = 320 + __builtin_ctzll(q5); q5 &= q5 - 1; } \
    else if (q6) { JV = 384 + __builtin_ctzll(q6); q6 &= q6 - 1; } \
    else JV = 400;                                             \
  } while (0)

// one hidden spike applied to this lane's output component (branchless; exact op order)
#define STEP(WV)                                   \
  do {                                             \
    float mn_ = __fadd_rn(h2, (WV));               \
    bool f_ = (mn_ >= 0.5f);                       \
    cntf = f_ ? (cntf + 1.0f) : cntf;              \
    h2 = f_ ? 0.0f : mn_;                          \
  } while (0)

template <bool TR>
__global__ __launch_bounds__(512) void snn_main(
    const float* __restrict__ ET, const int* __restrict__ EP,
    const float* __restrict__ W1x, const float* __restrict__ b1,
    const float* __restrict__ W2, const float* __restrict__ b2,
    float* __restrict__ out) {
  __shared__ float s_W2c[401 * 16];                    // W2.T + b2/400, padded; row 400 = zeros
  __shared__ unsigned long long s_masks[2][CH][8];     // fired masks, double-buffered
  __shared__ float s_dec1[2][CH];                      // layer-1 decay per event
  __shared__ float s_dec2[2][CH];                      // layer-2 decay per event

  const int tid = threadIdx.x;
  const int b = blockIdx.x;
  const int eb = b * NE;

  // build W2c table: W2c[j][k] = W2[k][j] + b2[k]/400 (cols 10..15 and row 400 are zero)
  for (int i = tid; i < 401 * 16; i += 512) {
    int row = i >> 4, col = i & 15;
    float v = 0.0f;
    if (row < DH && col < 10) v = __fadd_rn(W2[col * DH + row], __fdiv_rn(b2[col], 400.0f));
    s_W2c[i] = v;
  }

  const bool isProd = (tid < 448);   // waves 0..6 produce, wave 7 consumes
  const int lane = tid & 63;
  const int wv = tid >> 6;
  const bool act = (tid < DH);

  // ---- producer state ----
  float m1 = 0.0f;
  float b1v = act ? __fdiv_rn(b1[tid < DH ? tid : DH - 1], 784.0f) : 0.0f;
  float wA = 0.0f, wB = 0.0f;
  if (isProd) {
    int p0 = EP[eb + 0];
    int p1 = EP[eb + 1];
    wA = TR ? W1x[p0 * DH + tid] : W1x[(tid < DH ? tid : DH - 1) * DIN + p0];
    wB = TR ? W1x[p1 * DH + tid] : W1x[(tid < DH ? tid : DH - 1) * DIN + p1];
  }

  // ---- consumer state ----
  float h2 = 0.0f, cntf = 0.0f;
  const int kk = lane & 15;

  __syncthreads();  // W2c table ready

  for (int it = 0; it <= NCHUNK; ++it) {
    // phase A: decay factors for chunk `it` (wave 0: lanes 0..31 dec1, lanes 32..63 dec2)
    if (it < NCHUNK) {
      if (tid < CH) {
        int ge = it * CH + tid;
        float t = ET[eb + ge];
        float tp = (ge > 0) ? ET[eb + ge - 1] : 0.0f;
        s_dec1[it & 1][tid] = expf(__fdiv_rn(-(t - tp), TAUF));
      } else if (tid < 2 * CH) {
        int li = tid - CH;
        int ge = it * CH + li;
        float t = ET[eb + ge];
        float th = __fadd_rn(t, 0.1f);
        float thp = (ge > 0) ? __fadd_rn(ET[eb + ge - 1], 0.1f) : 0.0f;
        s_dec2[it & 1][li] = expf(__fdiv_rn(-(th - thp), TAUF));
      }
    }
    __syncthreads();

    if (isProd) {
      if (it < NCHUNK) {
        const int buf = it & 1;
        float dv[CH];
#pragma unroll
        for (int e = 0; e < CH; ++e) dv[e] = s_dec1[buf][e];
#pragma unroll
        for (int e = 0; e < CH; ++e) {
          int g = it * CH + e;
          // prefetch gather row two events ahead (p sequence is input-known)
          float wN = 0.0f;
          if (g + 2 < NE) {
            int pn = EP[eb + g + 2];
            wN = TR ? W1x[pn * DH + tid] : W1x[(tid < DH ? tid : DH - 1) * DIN + pn];
          }
          // exact reference order: ((m*e) + w) + b, no FMA contraction
          float mm = __fmul_rn(m1, dv[e]);
          mm = __fadd_rn(mm, wA);
          mm = __fadd_rn(mm, b1v);
          bool fired = act && (mm >= 0.5f);
          unsigned long long bal = __ballot(fired);
          m1 = fired ? 0.0f : mm;
          if (lane == 0) s_masks[buf][e][wv] = bal;
          wA = wB;
          wB = wN;
        }
      }
    } else {
      if (it >= 1) {
        const int buf2 = (it - 1) & 1;
        // current-event mask regs (prefetched)
        unsigned long long c0 = s_masks[buf2][0][0];
        unsigned long long c1 = s_masks[buf2][0][1];
        unsigned long long c2 = s_masks[buf2][0][2];
        unsigned long long c3 = s_masks[buf2][0][3];
        unsigned long long c4 = s_masks[buf2][0][4];
        unsigned long long c5 = s_masks[buf2][0][5];
        unsigned long long c6 = s_masks[buf2][0][6];
        float cd = s_dec2[buf2][0];
        for (int e = 0; e < CH; ++e) {
          unsigned long long n0 = 0, n1 = 0, n2 = 0, n3 = 0, n4 = 0, n5 = 0, n6 = 0;
          float nd = 0.0f;
          if (e + 1 < CH) {  // issue next event's mask loads before this event's chain
            n0 = s_masks[buf2][e + 1][0];
            n1 = s_masks[buf2][e + 1][1];
            n2 = s_masks[buf2][e + 1][2];
            n3 = s_masks[buf2][e + 1][3];
            n4 = s_masks[buf2][e + 1][4];
            n5 = s_masks[buf2][e + 1][5];
            n6 = s_masks[buf2][e + 1][6];
            nd = s_dec2[buf2][e + 1];
          }
          unsigned long long q0 = rfl64(c0), q1 = rfl64(c1), q2 = rfl64(c2), q3 = rfl64(c3);
          unsigned long long q4 = rfl64(c4), q5 = rfl64(c5), q6 = rfl64(c6);
          h2 = __fmul_rn(h2, cd);  // layer-2 decay before the hidden-event scan
          while (q0 | q1 | q2 | q3 | q4 | q5 | q6) {
            int j0, j1, j2, j3, j4, j5, j6, j7;
            NEXTJ(j0); NEXTJ(j1); NEXTJ(j2); NEXTJ(j3);
            NEXTJ(j4); NEXTJ(j5); NEXTJ(j6); NEXTJ(j7);
            float w0 = s_W2c[j0 * 16 + kk];
            float w1 = s_W2c[j1 * 16 + kk];
            float w2 = s_W2c[j2 * 16 + kk];
            float w3 = s_W2c[j3 * 16 + kk];
            float w4 = s_W2c[j4 * 16 + kk];
            float w5 = s_W2c[j5 * 16 + kk];
            float w6 = s_W2c[j6 * 16 + kk];
            float w7 = s_W2c[j7 * 16 + kk];
            // --- speculative fast path ------------------------------------
            // Sequential prefix sums are EXACTLY the mn_ values STEP would
            // compute if no reset fires anywhere in the batch (h2 < 0.5 is a
            // loop invariant; dummy w=0 adds are bit-exact no-ops).
            float p0 = __fadd_rn(h2, w0);
            float p1 = __fadd_rn(p0, w1);
            float p2 = __fadd_rn(p1, w2);
            float p3 = __fadd_rn(p2, w3);
            float p4 = __fadd_rn(p3, w4);
            float p5 = __fadd_rn(p4, w5);
            float p6 = __fadd_rn(p5, w6);
            float p7 = __fadd_rn(p6, w7);
            bool anyFire = (p0 >= 0.5f) | (p1 >= 0.5f) | (p2 >= 0.5f) | (p3 >= 0.5f) |
                           (p4 >= 0.5f) | (p5 >= 0.5f) | (p6 >= 0.5f) | (p7 >= 0.5f);
            if (!anyFire) {
              h2 = p7;  // bit-exact: no reset => h2 after batch == p7, cnt unchanged
            } else {
              // exact replay with resets (rare)
              STEP(w0); STEP(w1); STEP(w2); STEP(w3);
              STEP(w4); STEP(w5); STEP(w6); STEP(w7);
            }
          }
          c0 = n0; c1 = n1; c2 = n2; c3 = n3; c4 = n4; c5 = n5; c6 = n6; cd = nd;
        }
      }
    }
    __syncthreads();
  }

  if (!isProd && lane < 10) out[b * 10 + lane] = __fmul_rn(cntf, 0.015625f);
}

extern "C" void kernel_launch(void* const* d_in, const int* in_sizes, int n_in,
                              void* d_out, int out_size, void* d_ws, size_t ws_size,
                              hipStream_t stream) {
  const float* ET = (const float*)d_in[0];
  const int* EP = (const int*)d_in[1];
  const float* W1 = (const float*)d_in[2];
  const float* b1 = (const float*)d_in[3];
  const float* W2 = (const float*)d_in[4];
  const float* b2 = (const float*)d_in[5];
  float* out = (float*)d_out;

  const size_t need = (size_t)(DIN * DH + 64) * sizeof(float);
  if (ws_size >= need) {
    float* W1T = (float*)d_ws;
    hipLaunchKernelGGL(prep_transpose, dim3((DIN * DH + 64 + 255) / 256), dim3(256), 0, stream,
                       W1, W1T);
    hipLaunchKernelGGL((snn_main<true>), dim3(256), dim3(512), 0, stream,
                       ET, EP, W1T, b1, W2, b2, out);
  } else {
    // fallback: gather directly from W1 (uncoalesced but correct)
    hipLaunchKernelGGL((snn_main<false>), dim3(256), dim3(512), 0, stream,
                       ET, EP, W1, b1, W2, b2, out);
  }
}

// Round 5
// 1838.030 us; speedup vs baseline: 1.0413x; 1.0413x over previous
//
#include <hip/hip_runtime.h>

#define CH 32        // events per chunk
#define NCHUNK 32    // 1024 / CH
#define NE 1024
#define DH 400
#define DIN 784
#define PF 8         // W1-row prefetch depth (CH % PF == 0 so pipe index e&7 is compile-time)

// TAU = -1/ln(0.2) as the reference's Python double, rounded to f32 (JAX weak-type promotion)
#define TAUF ((float)0.6213349345596119)

// -------- prep: transpose W1 [400,784] -> W1T [784,400] in workspace (+64 zero pad) --------
__global__ void prep_transpose(const float* __restrict__ W1, float* __restrict__ W1T) {
  int idx = blockIdx.x * 256 + threadIdx.x;
  const int total = DIN * DH;
  if (idx < total) {
    int p = idx / DH;
    int j = idx - p * DH;
    W1T[idx] = W1[j * DIN + p];
  } else if (idx < total + 64) {
    W1T[idx] = 0.0f;  // pad so producer threads 400..447 stay in-bounds
  }
}

__device__ __forceinline__ unsigned long long rfl64(unsigned long long x) {
  unsigned int lo = __builtin_amdgcn_readfirstlane((unsigned int)(x & 0xffffffffull));
  unsigned int hi = __builtin_amdgcn_readfirstlane((unsigned int)(x >> 32));
  return (((unsigned long long)hi) << 32) | (unsigned long long)lo;
}

// extract next fired neuron index in ascending j order; 400 = dummy (zero weight row)
#define NEXTJ(JV)                                              \
  do {                                                         \
    if (q0)      { JV = __builtin_ctzll(q0);       q0 &= q0 - 1; } \
    else if (q1) { JV = 64 + __builtin_ctzll(q1);  q1 &= q1 - 1; } \
    else if (q2) { JV = 128 + __builtin_ctzll(q2); q2 &= q2 - 1; } \
    else if (q3) { JV = 192 + __builtin_ctzll(q3); q3 &= q3 - 1; } \
    else if (q4) { JV = 256 + __builtin_ctzll(q4); q4 &= q4 - 1; } \
    else if (q5) { JV = 320 + __builtin_ctzll(q5); q5 &= q5 - 1; } \
    else if (q6) { JV = 384 + __builtin_ctzll(q6); q6 &= q6 - 1; } \
    else JV = 400;                                             \
  } while (0)

// one hidden spike applied to this lane's output component (branchless; exact op order)
#define STEP(WV)                                   \
  do {                                             \
    float mn_ = __fadd_rn(h2, (WV));               \
    bool f_ = (mn_ >= 0.5f);                       \
    cntf = f_ ? (cntf + 1.0f) : cntf;              \
    h2 = f_ ? 0.0f : mn_;                          \
  } while (0)

template <bool TR>
__global__ __launch_bounds__(512, 2) void snn_main(
    const float* __restrict__ ET, const int* __restrict__ EP,
    const float* __restrict__ W1x, const float* __restrict__ b1,
    const float* __restrict__ W2, const float* __restrict__ b2,
    float* __restrict__ out) {
  __shared__ float s_W2c[401 * 16];                    // W2.T + b2/400, padded; row 400 = zeros
  __shared__ unsigned long long s_masks[2][CH][8];     // fired masks, double-buffered
  __shared__ float s_dec1[NE];                         // ALL layer-1 decay factors (precomputed)
  __shared__ float s_dec2[NE];                         // ALL layer-2 decay factors (precomputed)
  __shared__ int s_EP[NE];                             // ALL event pixels (staged once)

  const int tid = threadIdx.x;
  const int b = blockIdx.x;
  const int eb = b * NE;

  // ---- preamble: W2c table + EP staging + ALL decay factors (was per-chunk phase A) ----
  for (int i = tid; i < 401 * 16; i += 512) {
    int row = i >> 4, col = i & 15;
    float v = 0.0f;
    if (row < DH && col < 10) v = __fadd_rn(W2[col * DH + row], __fdiv_rn(b2[col], 400.0f));
    s_W2c[i] = v;
  }
  for (int i = tid; i < NE; i += 512) {
    s_EP[i] = EP[eb + i];
    float t = ET[eb + i];
    float tp = (i > 0) ? ET[eb + i - 1] : 0.0f;
    s_dec1[i] = expf(__fdiv_rn(-(t - tp), TAUF));      // exact expr as validated baseline
    float th = __fadd_rn(t, 0.1f);
    float thp = (i > 0) ? __fadd_rn(tp, 0.1f) : 0.0f;
    s_dec2[i] = expf(__fdiv_rn(-(th - thp), TAUF));
  }

  const bool isProd = (tid < 448);   // waves 0..6 produce, wave 7 consumes
  const int lane = tid & 63;
  const int wv = tid >> 6;
  const bool act = (tid < DH);

  // ---- producer state ----
  float m1 = 0.0f;
  float b1v = act ? __fdiv_rn(b1[tid < DH ? tid : DH - 1], 784.0f) : 0.0f;
  float wp[PF];                      // W1 rows, loaded 8 events ahead (constant-indexed)
  int pnP[PF];                       // pixel indices, read from LDS 16 events ahead

  // ---- consumer state ----
  float h2 = 0.0f, cntf = 0.0f;
  const int kk = lane & 15;

  __syncthreads();  // W2c / s_EP / decays ready

  if (isProd) {
#pragma unroll
    for (int i = 0; i < PF; ++i) {
      int p = s_EP[i];
      wp[i] = TR ? W1x[p * DH + tid] : W1x[(tid < DH ? tid : DH - 1) * DIN + p];
      pnP[i] = s_EP[i + PF];
    }
  } else {
#pragma unroll
    for (int i = 0; i < PF; ++i) { wp[i] = 0.0f; pnP[i] = 0; }
  }

  for (int it = 0; it <= NCHUNK; ++it) {
    if (isProd) {
      if (it < NCHUNK) {
        const int buf = it & 1;
        const int gbase = it * CH;
#pragma unroll
        for (int e = 0; e < CH; ++e) {
          const int g = gbase + e;
          const int s = e & (PF - 1);  // == g & (PF-1): CH multiple of PF
          // exact reference order: ((m*e) + w) + b, no FMA contraction
          float mm = __fmul_rn(m1, s_dec1[g]);
          mm = __fadd_rn(mm, wp[s]);
          mm = __fadd_rn(mm, b1v);
          bool fired = act && (mm >= 0.5f);
          unsigned long long bal = __ballot(fired);
          m1 = fired ? 0.0f : mm;
          if (lane == 0) s_masks[buf][e][wv] = bal;
          // refill pipe: issue row g+PF (address from LDS — no global dependent chain)
          int pn = pnP[s];
          wp[s] = TR ? W1x[pn * DH + tid] : W1x[(tid < DH ? tid : DH - 1) * DIN + pn];
          pnP[s] = s_EP[(g + 2 * PF) & (NE - 1)];  // wrap at tail: loaded, never consumed
        }
      }
    } else {
      if (it >= 1) {
        const int buf2 = (it - 1) & 1;
        const int gb2 = (it - 1) * CH;
        // current-event mask regs (prefetched one event ahead)
        unsigned long long c0 = s_masks[buf2][0][0];
        unsigned long long c1 = s_masks[buf2][0][1];
        unsigned long long c2 = s_masks[buf2][0][2];
        unsigned long long c3 = s_masks[buf2][0][3];
        unsigned long long c4 = s_masks[buf2][0][4];
        unsigned long long c5 = s_masks[buf2][0][5];
        unsigned long long c6 = s_masks[buf2][0][6];
        float cd = s_dec2[gb2];
        for (int e = 0; e < CH; ++e) {
          unsigned long long n0 = 0, n1 = 0, n2 = 0, n3 = 0, n4 = 0, n5 = 0, n6 = 0;
          float nd = 0.0f;
          if (e + 1 < CH) {  // issue next event's mask loads before this event's chain
            n0 = s_masks[buf2][e + 1][0];
            n1 = s_masks[buf2][e + 1][1];
            n2 = s_masks[buf2][e + 1][2];
            n3 = s_masks[buf2][e + 1][3];
            n4 = s_masks[buf2][e + 1][4];
            n5 = s_masks[buf2][e + 1][5];
            n6 = s_masks[buf2][e + 1][6];
            nd = s_dec2[gb2 + e + 1];
          }
          unsigned long long q0 = rfl64(c0), q1 = rfl64(c1), q2 = rfl64(c2), q3 = rfl64(c3);
          unsigned long long q4 = rfl64(c4), q5 = rfl64(c5), q6 = rfl64(c6);
          h2 = __fmul_rn(h2, cd);  // layer-2 decay before the hidden-event scan
          while (q0 | q1 | q2 | q3 | q4 | q5 | q6) {
            int j0, j1, j2, j3, j4, j5, j6, j7;
            NEXTJ(j0); NEXTJ(j1); NEXTJ(j2); NEXTJ(j3);
            NEXTJ(j4); NEXTJ(j5); NEXTJ(j6); NEXTJ(j7);
            float w0 = s_W2c[j0 * 16 + kk];
            float w1 = s_W2c[j1 * 16 + kk];
            float w2 = s_W2c[j2 * 16 + kk];
            float w3 = s_W2c[j3 * 16 + kk];
            float w4 = s_W2c[j4 * 16 + kk];
            float w5 = s_W2c[j5 * 16 + kk];
            float w6 = s_W2c[j6 * 16 + kk];
            float w7 = s_W2c[j7 * 16 + kk];
            // --- speculative fast path ------------------------------------
            // Sequential prefix sums are EXACTLY the mn_ values STEP would
            // compute if no reset fires anywhere in the batch (h2 < 0.5 is a
            // loop invariant; dummy w=0 adds are bit-exact no-ops).
            float p0 = __fadd_rn(h2, w0);
            float p1 = __fadd_rn(p0, w1);
            float p2 = __fadd_rn(p1, w2);
            float p3 = __fadd_rn(p2, w3);
            float p4 = __fadd_rn(p3, w4);
            float p5 = __fadd_rn(p4, w5);
            float p6 = __fadd_rn(p5, w6);
            float p7 = __fadd_rn(p6, w7);
            bool anyFire = (p0 >= 0.5f) | (p1 >= 0.5f) | (p2 >= 0.5f) | (p3 >= 0.5f) |
                           (p4 >= 0.5f) | (p5 >= 0.5f) | (p6 >= 0.5f) | (p7 >= 0.5f);
            if (!anyFire) {
              h2 = p7;  // bit-exact: no reset => h2 after batch == p7, cnt unchanged
            } else {
              // exact replay with resets (rare)
              STEP(w0); STEP(w1); STEP(w2); STEP(w3);
              STEP(w4); STEP(w5); STEP(w6); STEP(w7);
            }
          }
          c0 = n0; c1 = n1; c2 = n2; c3 = n3; c4 = n4; c5 = n5; c6 = n6; cd = nd;
        }
      }
    }
    // single barrier per iteration: producer buf (it&1) and consumer buf ((it-1)&1)
    // are disjoint within an iteration; buffer reuse is separated by this barrier.
    __syncthreads();
  }

  if (!isProd && lane < 10) out[b * 10 + lane] = __fmul_rn(cntf, 0.015625f);
}

extern "C" void kernel_launch(void* const* d_in, const int* in_sizes, int n_in,
                              void* d_out, int out_size, void* d_ws, size_t ws_size,
                              hipStream_t stream) {
  const float* ET = (const float*)d_in[0];
  const int* EP = (const int*)d_in[1];
  const float* W1 = (const float*)d_in[2];
  const float* b1 = (const float*)d_in[3];
  const float* W2 = (const float*)d_in[4];
  const float* b2 = (const float*)d_in[5];
  float* out = (float*)d_out;

  const size_t need = (size_t)(DIN * DH + 64) * sizeof(float);
  if (ws_size >= need) {
    float* W1T = (float*)d_ws;
    hipLaunchKernelGGL(prep_transpose, dim3((DIN * DH + 64 + 255) / 256), dim3(256), 0, stream,
                       W1, W1T);
    hipLaunchKernelGGL((snn_main<true>), dim3(256), dim3(512), 0, stream,
                       ET, EP, W1T, b1, W2, b2, out);
  } else {
    // fallback: gather directly from W1 (uncoalesced but correct)
    hipLaunchKernelGGL((snn_main<false>), dim3(256), dim3(512), 0, stream,
                       ET, EP, W1, b1, W2, b2, out);
  }
}

// Round 6
// 562.111 us; speedup vs baseline: 3.4051x; 3.2699x over previous
//
#include <hip/hip_runtime.h>

#define CH 32        // events per chunk
#define NCHUNK 32    // 1024 / CH
#define NE 1024
#define DH 400
#define DIN 784
#define PF 8         // W1-row prefetch depth (CH % PF == 0 so pipe index e&7 is compile-time)

// TAU = -1/ln(0.2) as the reference's Python double, rounded to f32 (JAX weak-type promotion)
#define TAUF ((float)0.6213349345596119)

// -------- prep: transpose W1 [400,784] -> W1T [784,400] in workspace (+64 zero pad) --------
__global__ void prep_transpose(const float* __restrict__ W1, float* __restrict__ W1T) {
  int idx = blockIdx.x * 256 + threadIdx.x;
  const int total = DIN * DH;
  if (idx < total) {
    int p = idx / DH;
    int j = idx - p * DH;
    W1T[idx] = W1[j * DIN + p];
  } else if (idx < total + 64) {
    W1T[idx] = 0.0f;  // pad so producer threads 400..447 stay in-bounds
  }
}

// one hidden spike applied to this lane's output component (branchless; exact op order)
#define STEP(WV)                                   \
  do {                                             \
    float mn_ = __fadd_rn(h2, (WV));               \
    bool f_ = (mn_ >= 0.5f);                       \
    cntf = f_ ? (cntf + 1.0f) : cntf;              \
    h2 = f_ ? 0.0f : mn_;                          \
  } while (0)

// predicated word-select step for rank-select (branchless)
#define WSEL(PW, CW, WB)                            \
  do {                                              \
    bool c_ = (N >= (PW));                          \
    q = c_ ? (CW) : q;                              \
    r = c_ ? (N - (PW)) : r;                        \
    wb = c_ ? (WB) : wb;                            \
  } while (0)

template <bool TR>
__global__ __launch_bounds__(512, 2) void snn_main(
    const float* __restrict__ ET, const int* __restrict__ EP,
    const float* __restrict__ W1x, const float* __restrict__ b1,
    const float* __restrict__ W2, const float* __restrict__ b2,
    float* __restrict__ out) {
  __shared__ float s_W2c[401 * 16];                    // W2.T + b2/400, padded; row 400 = zeros
  __shared__ unsigned long long s_masks[2][CH][8];     // fired masks, double-buffered
  __shared__ float s_dec1[NE];                         // ALL layer-1 decay factors (precomputed)
  __shared__ float s_dec2[NE];                         // ALL layer-2 decay factors (precomputed)
  __shared__ int s_EP[NE];                             // ALL event pixels (staged once)
  __shared__ __align__(16) int s_spk[64];              // extracted spike indices (consumer wave)

  const int tid = threadIdx.x;
  const int b = blockIdx.x;
  const int eb = b * NE;

  // ---- preamble: W2c table + EP staging + ALL decay factors ----
  for (int i = tid; i < 401 * 16; i += 512) {
    int row = i >> 4, col = i & 15;
    float v = 0.0f;
    if (row < DH && col < 10) v = __fadd_rn(W2[col * DH + row], __fdiv_rn(b2[col], 400.0f));
    s_W2c[i] = v;
  }
  for (int i = tid; i < NE; i += 512) {
    s_EP[i] = EP[eb + i];
    float t = ET[eb + i];
    float tp = (i > 0) ? ET[eb + i - 1] : 0.0f;
    s_dec1[i] = expf(__fdiv_rn(-(t - tp), TAUF));      // exact expr as validated baseline
    float th = __fadd_rn(t, 0.1f);
    float thp = (i > 0) ? __fadd_rn(tp, 0.1f) : 0.0f;
    s_dec2[i] = expf(__fdiv_rn(-(th - thp), TAUF));
  }

  const bool isProd = (tid < 448);   // waves 0..6 produce, wave 7 consumes
  const int lane = tid & 63;
  const int wv = tid >> 6;
  const bool act = (tid < DH);

  // ---- producer state ----
  float m1 = 0.0f;
  float b1v = act ? __fdiv_rn(b1[tid < DH ? tid : DH - 1], 784.0f) : 0.0f;
  float wp[PF];                      // W1 rows, loaded 8 events ahead (constant-indexed)
  int pnP[PF];                       // pixel indices, read from LDS 16 events ahead

  // ---- consumer state ----
  float h2 = 0.0f, cntf = 0.0f;
  const int kk = lane & 15;

  __syncthreads();  // W2c / s_EP / decays ready

  if (isProd) {
#pragma unroll
    for (int i = 0; i < PF; ++i) {
      int p = s_EP[i];
      wp[i] = TR ? W1x[p * DH + tid] : W1x[(tid < DH ? tid : DH - 1) * DIN + p];
      pnP[i] = s_EP[i + PF];
    }
  } else {
#pragma unroll
    for (int i = 0; i < PF; ++i) { wp[i] = 0.0f; pnP[i] = 0; }
  }

  for (int it = 0; it <= NCHUNK; ++it) {
    if (isProd) {
      if (it < NCHUNK) {
        const int buf = it & 1;
        const int gbase = it * CH;
#pragma unroll
        for (int e = 0; e < CH; ++e) {
          const int g = gbase + e;
          const int s = e & (PF - 1);  // == g & (PF-1): CH multiple of PF
          // exact reference order: ((m*e) + w) + b, no FMA contraction
          float mm = __fmul_rn(m1, s_dec1[g]);
          mm = __fadd_rn(mm, wp[s]);
          mm = __fadd_rn(mm, b1v);
          bool fired = act && (mm >= 0.5f);
          unsigned long long bal = __ballot(fired);
          m1 = fired ? 0.0f : mm;
          if (lane == 0) s_masks[buf][e][wv] = bal;
          // refill pipe: issue row g+PF (address from LDS — no global dependent chain)
          int pn = pnP[s];
          wp[s] = TR ? W1x[pn * DH + tid] : W1x[(tid < DH ? tid : DH - 1) * DIN + pn];
          pnP[s] = s_EP[(g + 2 * PF) & (NE - 1)];  // wrap at tail: loaded, never consumed
        }
      }
    } else {
      if (it >= 1) {
        const int buf2 = (it - 1) & 1;
        const int gb2 = (it - 1) * CH;
        // current-event masks (per-lane regs; values are wave-uniform)
        unsigned long long c0 = s_masks[buf2][0][0];
        unsigned long long c1 = s_masks[buf2][0][1];
        unsigned long long c2 = s_masks[buf2][0][2];
        unsigned long long c3 = s_masks[buf2][0][3];
        unsigned long long c4 = s_masks[buf2][0][4];
        unsigned long long c5 = s_masks[buf2][0][5];
        unsigned long long c6 = s_masks[buf2][0][6];
        float cd = s_dec2[gb2];
        for (int e = 0; e < CH; ++e) {
          unsigned long long n0 = 0, n1 = 0, n2 = 0, n3 = 0, n4 = 0, n5 = 0, n6 = 0;
          float nd = 0.0f;
          if (e + 1 < CH) {  // issue next event's mask loads before this event's work
            n0 = s_masks[buf2][e + 1][0];
            n1 = s_masks[buf2][e + 1][1];
            n2 = s_masks[buf2][e + 1][2];
            n3 = s_masks[buf2][e + 1][3];
            n4 = s_masks[buf2][e + 1][4];
            n5 = s_masks[buf2][e + 1][5];
            n6 = s_masks[buf2][e + 1][6];
            nd = s_dec2[gb2 + e + 1];
          }
          h2 = __fmul_rn(h2, cd);  // layer-2 decay before the hidden-event scan
          // ---- wave-parallel branchless spike extraction (replaces NEXTJ cascade) ----
          unsigned p0c = (unsigned)__popcll(c0);
          unsigned p1c = (unsigned)__popcll(c1);
          unsigned p2c = (unsigned)__popcll(c2);
          unsigned p3c = (unsigned)__popcll(c3);
          unsigned p4c = (unsigned)__popcll(c4);
          unsigned p5c = (unsigned)__popcll(c5);
          unsigned p6c = (unsigned)__popcll(c6);
          unsigned P1 = p0c, P2 = P1 + p1c, P3 = P2 + p2c, P4 = P3 + p3c;
          unsigned P5 = P4 + p4c, P6 = P5 + p5c;
          unsigned total = P6 + p6c;
          if (total) {
            for (unsigned done = 0; done < total; done += 64) {   // ≥2 rounds only if >64 fires
              unsigned N = done + (unsigned)lane;                 // lane L extracts spike #N
              unsigned long long q = c0;
              unsigned r = N, wb = 0;
              WSEL(P1, c1, 64);  WSEL(P2, c2, 128); WSEL(P3, c3, 192);
              WSEL(P4, c4, 256); WSEL(P5, c5, 320); WSEL(P6, c6, 384);
              // rank-select bit #r within q (branchless binary descent)
              unsigned lo = (unsigned)q, hi = (unsigned)(q >> 32);
              unsigned pc = (unsigned)__popc(lo);
              bool gg = r >= pc; unsigned base = gg ? 32u : 0u;
              unsigned x = gg ? hi : lo; r = gg ? r - pc : r;
              pc = (unsigned)__popc(x & 0xFFFFu); gg = r >= pc; base += gg ? 16u : 0u;
              x = gg ? (x >> 16) : (x & 0xFFFFu); r = gg ? r - pc : r;
              pc = (unsigned)__popc(x & 0xFFu); gg = r >= pc; base += gg ? 8u : 0u;
              x = gg ? (x >> 8) : (x & 0xFFu); r = gg ? r - pc : r;
              pc = (unsigned)__popc(x & 0xFu); gg = r >= pc; base += gg ? 4u : 0u;
              x = gg ? (x >> 4) : (x & 0xFu); r = gg ? r - pc : r;
              pc = (unsigned)__popc(x & 0x3u); gg = r >= pc; base += gg ? 2u : 0u;
              x = gg ? (x >> 2) : (x & 0x3u); r = gg ? r - pc : r;
              gg = r >= (x & 1u); base += gg ? 1u : 0u;
              int j = (int)(wb + base);
              j = (N < total) ? j : 400;       // pad with dummy zero-weight row
              s_spk[lane] = j;                 // spill ordered list (same wave: lgkm dep only)
              unsigned cnt = total - done; cnt = cnt > 64u ? 64u : cnt;
              unsigned nb = (cnt + 7u) >> 3;
              for (unsigned bb = 0; bb < nb; ++bb) {
                const int4* sp = (const int4*)(s_spk + bb * 8);
                int4 ja = sp[0], jb = sp[1];   // 8 spike indices (uniform broadcast reads)
                float w0 = s_W2c[ja.x * 16 + kk];
                float w1 = s_W2c[ja.y * 16 + kk];
                float w2 = s_W2c[ja.z * 16 + kk];
                float w3 = s_W2c[ja.w * 16 + kk];
                float w4 = s_W2c[jb.x * 16 + kk];
                float w5 = s_W2c[jb.y * 16 + kk];
                float w6 = s_W2c[jb.z * 16 + kk];
                float w7 = s_W2c[jb.w * 16 + kk];
                // --- speculative fast path (bit-exact; h2 < 0.5 invariant) ---
                float q0f = __fadd_rn(h2, w0);
                float q1f = __fadd_rn(q0f, w1);
                float q2f = __fadd_rn(q1f, w2);
                float q3f = __fadd_rn(q2f, w3);
                float q4f = __fadd_rn(q3f, w4);
                float q5f = __fadd_rn(q4f, w5);
                float q6f = __fadd_rn(q5f, w6);
                float q7f = __fadd_rn(q6f, w7);
                bool anyFire = (q0f >= 0.5f) | (q1f >= 0.5f) | (q2f >= 0.5f) | (q3f >= 0.5f) |
                               (q4f >= 0.5f) | (q5f >= 0.5f) | (q6f >= 0.5f) | (q7f >= 0.5f);
                if (!anyFire) {
                  h2 = q7f;  // no reset => bit-identical to STEP chain
                } else {
                  STEP(w0); STEP(w1); STEP(w2); STEP(w3);
                  STEP(w4); STEP(w5); STEP(w6); STEP(w7);
                }
              }
            }
          }
          c0 = n0; c1 = n1; c2 = n2; c3 = n3; c4 = n4; c5 = n5; c6 = n6; cd = nd;
        }
      }
    }
    // single barrier per iteration: producer buf (it&1) and consumer buf ((it-1)&1)
    // are disjoint within an iteration; buffer reuse is separated by this barrier.
    __syncthreads();
  }

  if (!isProd && lane < 10) out[b * 10 + lane] = __fmul_rn(cntf, 0.015625f);
}

extern "C" void kernel_launch(void* const* d_in, const int* in_sizes, int n_in,
                              void* d_out, int out_size, void* d_ws, size_t ws_size,
                              hipStream_t stream) {
  const float* ET = (const float*)d_in[0];
  const int* EP = (const int*)d_in[1];
  const float* W1 = (const float*)d_in[2];
  const float* b1 = (const float*)d_in[3];
  const float* W2 = (const float*)d_in[4];
  const float* b2 = (const float*)d_in[5];
  float* out = (float*)d_out;

  const size_t need = (size_t)(DIN * DH + 64) * sizeof(float);
  if (ws_size >= need) {
    float* W1T = (float*)d_ws;
    hipLaunchKernelGGL(prep_transpose, dim3((DIN * DH + 64 + 255) / 256), dim3(256), 0, stream,
                       W1, W1T);
    hipLaunchKernelGGL((snn_main<true>), dim3(256), dim3(512), 0, stream,
                       ET, EP, W1T, b1, W2, b2, out);
  } else {
    // fallback: gather directly from W1 (uncoalesced but correct)
    hipLaunchKernelGGL((snn_main<false>), dim3(256), dim3(512), 0, stream,
                       ET, EP, W1, b1, W2, b2, out);
  }
}

// Round 7
// 253.362 us; speedup vs baseline: 7.5545x; 2.2186x over previous
//
#include <hip/hip_runtime.h>

#define CH 32        // events per chunk
#define NCHUNK 32    // 1024 / CH
#define NE 1024
#define DH 400
#define DIN 784
#define PF 8         // W1-row prefetch depth (CH % PF == 0 so pipe index e&7 is compile-time)

// TAU = -1/ln(0.2) as the reference's Python double, rounded to f32 (JAX weak-type promotion)
#define TAUF ((float)0.6213349345596119)

// -------- prep: transpose W1 [400,784] -> W1T [784,400] in workspace (+64 zero pad) --------
__global__ void prep_transpose(const float* __restrict__ W1, float* __restrict__ W1T) {
  int idx = blockIdx.x * 256 + threadIdx.x;
  const int total = DIN * DH;
  if (idx < total) {
    int p = idx / DH;
    int j = idx - p * DH;
    W1T[idx] = W1[j * DIN + p];
  } else if (idx < total + 64) {
    W1T[idx] = 0.0f;  // pad so producer threads 400..447 stay in-bounds
  }
}

// one hidden spike applied to this lane's output component (branchless; exact op order)
#define STEP(WV)                                   \
  do {                                             \
    float mn_ = __fadd_rn(h2, (WV));               \
    bool f_ = (mn_ >= 0.5f);                       \
    cntf = f_ ? (cntf + 1.0f) : cntf;              \
    h2 = f_ ? 0.0f : mn_;                          \
  } while (0)

// speculative batch of 8 (bit-exact: h2 < 0.5 invariant; zero-weight dummies are no-ops)
#define SPEC8(W0, W1, W2, W3, W4, W5, W6, W7)                                  \
  do {                                                                         \
    float q0f = __fadd_rn(h2, (W0));                                           \
    float q1f = __fadd_rn(q0f, (W1));                                          \
    float q2f = __fadd_rn(q1f, (W2));                                          \
    float q3f = __fadd_rn(q2f, (W3));                                          \
    float q4f = __fadd_rn(q3f, (W4));                                          \
    float q5f = __fadd_rn(q4f, (W5));                                          \
    float q6f = __fadd_rn(q5f, (W6));                                          \
    float q7f = __fadd_rn(q6f, (W7));                                          \
    bool anyF = (q0f >= 0.5f) | (q1f >= 0.5f) | (q2f >= 0.5f) | (q3f >= 0.5f) |\
                (q4f >= 0.5f) | (q5f >= 0.5f) | (q6f >= 0.5f) | (q7f >= 0.5f); \
    if (!anyF) {                                                               \
      h2 = q7f;                                                                \
    } else {                                                                   \
      STEP(W0); STEP(W1); STEP(W2); STEP(W3);                                  \
      STEP(W4); STEP(W5); STEP(W6); STEP(W7);                                  \
    }                                                                          \
  } while (0)

// predicated word-select step for rank-select (branchless)
#define WSEL(PW, CW, WB)                            \
  do {                                              \
    bool c_ = (N >= (PW));                          \
    q = c_ ? (CW) : q;                              \
    r = c_ ? (N - (PW)) : r;                        \
    wb = c_ ? (WB) : wb;                            \
  } while (0)

// rank-select bit #r within 64-bit q -> base (branchless binary descent)
#define RSEL64()                                                               \
  unsigned lo = (unsigned)q, hi = (unsigned)(q >> 32);                         \
  unsigned pc = (unsigned)__popc(lo);                                          \
  bool gg = r >= pc; unsigned base = gg ? 32u : 0u;                            \
  unsigned x = gg ? hi : lo; r = gg ? r - pc : r;                              \
  pc = (unsigned)__popc(x & 0xFFFFu); gg = r >= pc; base += gg ? 16u : 0u;     \
  x = gg ? (x >> 16) : (x & 0xFFFFu); r = gg ? r - pc : r;                     \
  pc = (unsigned)__popc(x & 0xFFu); gg = r >= pc; base += gg ? 8u : 0u;        \
  x = gg ? (x >> 8) : (x & 0xFFu); r = gg ? r - pc : r;                        \
  pc = (unsigned)__popc(x & 0xFu); gg = r >= pc; base += gg ? 4u : 0u;         \
  x = gg ? (x >> 4) : (x & 0xFu); r = gg ? r - pc : r;                         \
  pc = (unsigned)__popc(x & 0x3u); gg = r >= pc; base += gg ? 2u : 0u;         \
  x = gg ? (x >> 2) : (x & 0x3u); r = gg ? r - pc : r;                         \
  gg = r >= (x & 1u); base += gg ? 1u : 0u;

template <bool TR>
__global__ __launch_bounds__(512, 2) void snn_main(
    const float* __restrict__ ET, const int* __restrict__ EP,
    const float* __restrict__ W1x, const float* __restrict__ b1,
    const float* __restrict__ W2, const float* __restrict__ b2,
    float* __restrict__ out) {
  __shared__ float s_W2c[401 * 16];                    // W2.T + b2/400, padded; row 400 = zeros
  __shared__ unsigned long long s_masks[3][CH][8];     // fired masks, TRIPLE-buffered (%3)
  __shared__ float s_dec1[NE];                         // ALL layer-1 decay factors
  __shared__ float s_dec2[NE];                         // ALL layer-2 decay factors
  __shared__ int s_EP[NE];                             // ALL event pixels
  __shared__ __align__(16) int s_spklist[2][CH][64];   // ordered spike lists (stage 2 output)
  __shared__ float s_wlist[2][CH][256];                // pre-gathered weights: 16 slots x 16 comps
  __shared__ int s_spkcnt[2][CH];                      // spike counts per event
  __shared__ __align__(16) int s_spk2[64];             // consumer scratch for >64-fire path

  const int tid = threadIdx.x;
  const int b = blockIdx.x;
  const int eb = b * NE;

  // ---- preamble: W2c table + EP staging + ALL decay factors ----
  for (int i = tid; i < 401 * 16; i += 512) {
    int row = i >> 4, col = i & 15;
    float v = 0.0f;
    if (row < DH && col < 10) v = __fadd_rn(W2[col * DH + row], __fdiv_rn(b2[col], 400.0f));
    s_W2c[i] = v;
  }
  for (int i = tid; i < NE; i += 512) {
    s_EP[i] = EP[eb + i];
    float t = ET[eb + i];
    float tp = (i > 0) ? ET[eb + i - 1] : 0.0f;
    s_dec1[i] = expf(__fdiv_rn(-(t - tp), TAUF));      // exact expr as validated baseline
    float th = __fadd_rn(t, 0.1f);
    float thp = (i > 0) ? __fadd_rn(tp, 0.1f) : 0.0f;
    s_dec2[i] = expf(__fdiv_rn(-(th - thp), TAUF));
  }

  const bool isProd = (tid < 448);   // waves 0..6 produce+extract, wave 7 consumes
  const int lane = tid & 63;
  const int wv = tid >> 6;
  const bool act = (tid < DH);

  // ---- producer state ----
  float m1 = 0.0f;
  float b1v = act ? __fdiv_rn(b1[tid < DH ? tid : DH - 1], 784.0f) : 0.0f;
  float wp[PF];
  int pnP[PF];

  // ---- consumer state ----
  float h2 = 0.0f, cntf = 0.0f;
  const int kk = lane & 15;

  __syncthreads();  // W2c / s_EP / decays ready

  if (isProd) {
#pragma unroll
    for (int i = 0; i < PF; ++i) {
      int p = s_EP[i];
      wp[i] = TR ? W1x[p * DH + tid] : W1x[(tid < DH ? tid : DH - 1) * DIN + p];
      pnP[i] = s_EP[i + PF];
    }
  } else {
#pragma unroll
    for (int i = 0; i < PF; ++i) { wp[i] = 0.0f; pnP[i] = 0; }
  }

  // 3-stage pipeline: produce chunk it | extract chunk it-1 | consume chunk it-2
  for (int it = 0; it <= NCHUNK + 1; ++it) {
    if (isProd) {
      // ---- stage 1: masks for chunk it ----
      if (it < NCHUNK) {
        const int mb = it % 3;
        const int gbase = it * CH;
#pragma unroll
        for (int e = 0; e < CH; ++e) {
          const int g = gbase + e;
          const int s = e & (PF - 1);
          // exact reference order: ((m*e) + w) + b, no FMA contraction
          float mm = __fmul_rn(m1, s_dec1[g]);
          mm = __fadd_rn(mm, wp[s]);
          mm = __fadd_rn(mm, b1v);
          bool fired = act && (mm >= 0.5f);
          unsigned long long bal = __ballot(fired);
          m1 = fired ? 0.0f : mm;
          if (lane == 0) s_masks[mb][e][wv] = bal;
          int pn = pnP[s];
          wp[s] = TR ? W1x[pn * DH + tid] : W1x[(tid < DH ? tid : DH - 1) * DIN + pn];
          pnP[s] = s_EP[(g + 2 * PF) & (NE - 1)];  // wrap at tail: loaded, never consumed
        }
      }
      // ---- stage 2: extract chunk it-1 (7 waves share 32 events, stride 7) ----
      if (it >= 1 && it <= NCHUNK) {
        const int c = it - 1;
        const int mb = c % 3;
        const int lb = c & 1;
        for (int e = wv; e < CH; e += 7) {
          unsigned long long c0 = s_masks[mb][e][0];
          unsigned long long c1 = s_masks[mb][e][1];
          unsigned long long c2 = s_masks[mb][e][2];
          unsigned long long c3 = s_masks[mb][e][3];
          unsigned long long c4 = s_masks[mb][e][4];
          unsigned long long c5 = s_masks[mb][e][5];
          unsigned long long c6 = s_masks[mb][e][6];
          unsigned P1 = (unsigned)__popcll(c0);
          unsigned P2 = P1 + (unsigned)__popcll(c1);
          unsigned P3 = P2 + (unsigned)__popcll(c2);
          unsigned P4 = P3 + (unsigned)__popcll(c3);
          unsigned P5 = P4 + (unsigned)__popcll(c4);
          unsigned P6 = P5 + (unsigned)__popcll(c5);
          unsigned total = P6 + (unsigned)__popcll(c6);
          unsigned N = (unsigned)lane;                 // lane L extracts spike #L
          unsigned long long q = c0;
          unsigned r = N, wb = 0;
          WSEL(P1, c1, 64);  WSEL(P2, c2, 128); WSEL(P3, c3, 192);
          WSEL(P4, c4, 256); WSEL(P5, c5, 320); WSEL(P6, c6, 384);
          RSEL64();
          int j = (int)(wb + base);
          j = (N < total) ? j : DH;                    // dummy zero-weight row
          s_spklist[lb][e][lane] = j;
          if (lane == 0) s_spkcnt[lb][e] = (int)total;
          // pre-gather first 16 weight rows: pass p covers slots p*4..p*4+3
#pragma unroll
          for (int p = 0; p < 4; ++p) {
            int sl = p * 4 + (lane >> 4);
            int js = __builtin_amdgcn_ds_bpermute(sl << 2, j);
            float w = s_W2c[js * 16 + (lane & 15)];
            s_wlist[lb][e][sl * 16 + (lane & 15)] = w;  // addr = base + p*64 + lane: linear
          }
        }
      }
    } else {
      // ---- stage 3: consume chunk it-2 (constant-address LDS reads only) ----
      if (it >= 2) {
        const int c = it - 2;
        const int lb = c & 1;
        const int mb = c % 3;
        const int gb2 = c * CH;

        auto loadEvt = [&](int ee, int& tot, float& cdv, float (&w)[16]) {
          tot = s_spkcnt[lb][ee];
          cdv = s_dec2[gb2 + ee];
#pragma unroll
          for (int i = 0; i < 16; ++i) w[i] = s_wlist[lb][ee][i * 16 + kk];
        };
        auto procEvt = [&](int e, int tot, float cdv, float (&w)[16]) {
          h2 = __fmul_rn(h2, cdv);  // layer-2 decay before the hidden-event scan
          if (tot > 0) {
            SPEC8(w[0], w[1], w[2], w[3], w[4], w[5], w[6], w[7]);
            if (tot > 8) {
              SPEC8(w[8], w[9], w[10], w[11], w[12], w[13], w[14], w[15]);
            }
            if (tot > 16) {  // cold: remaining spikes from the list (P ~ 1e-4)
              int lim = tot < 64 ? tot : 64;
              for (int dn = 16; dn < lim; dn += 8) {
                const int4* sp = (const int4*)(&s_spklist[lb][e][dn]);
                int4 ja = sp[0], jb = sp[1];
                float v0 = s_W2c[ja.x * 16 + kk];
                float v1 = s_W2c[ja.y * 16 + kk];
                float v2 = s_W2c[ja.z * 16 + kk];
                float v3 = s_W2c[ja.w * 16 + kk];
                float v4 = s_W2c[jb.x * 16 + kk];
                float v5 = s_W2c[jb.y * 16 + kk];
                float v6 = s_W2c[jb.z * 16 + kk];
                float v7 = s_W2c[jb.w * 16 + kk];
                SPEC8(v0, v1, v2, v3, v4, v5, v6, v7);
              }
              if (tot > 64) {  // colder: re-extract rounds from still-live masks
                unsigned long long c0 = s_masks[mb][e][0];
                unsigned long long c1 = s_masks[mb][e][1];
                unsigned long long c2 = s_masks[mb][e][2];
                unsigned long long c3 = s_masks[mb][e][3];
                unsigned long long c4 = s_masks[mb][e][4];
                unsigned long long c5 = s_masks[mb][e][5];
                unsigned long long c6 = s_masks[mb][e][6];
                unsigned P1 = (unsigned)__popcll(c0);
                unsigned P2 = P1 + (unsigned)__popcll(c1);
                unsigned P3 = P2 + (unsigned)__popcll(c2);
                unsigned P4 = P3 + (unsigned)__popcll(c3);
                unsigned P5 = P4 + (unsigned)__popcll(c4);
                unsigned P6 = P5 + (unsigned)__popcll(c5);
                for (int done = 64; done < tot; done += 64) {
                  unsigned N = (unsigned)(done + lane);
                  unsigned long long q = c0;
                  unsigned r = N, wb = 0;
                  WSEL(P1, c1, 64);  WSEL(P2, c2, 128); WSEL(P3, c3, 192);
                  WSEL(P4, c4, 256); WSEL(P5, c5, 320); WSEL(P6, c6, 384);
                  RSEL64();
                  int j = (int)(wb + base);
                  j = (N < (unsigned)tot) ? j : DH;
                  s_spk2[lane] = j;
                  int cnt = tot - done; cnt = cnt > 64 ? 64 : cnt;
                  int nb2 = (cnt + 7) >> 3;
                  for (int bb = 0; bb < nb2; ++bb) {
                    const int4* sp = (const int4*)(s_spk2 + bb * 8);
                    int4 ja = sp[0], jb = sp[1];
                    float v0 = s_W2c[ja.x * 16 + kk];
                    float v1 = s_W2c[ja.y * 16 + kk];
                    float v2 = s_W2c[ja.z * 16 + kk];
                    float v3 = s_W2c[ja.w * 16 + kk];
                    float v4 = s_W2c[jb.x * 16 + kk];
                    float v5 = s_W2c[jb.y * 16 + kk];
                    float v6 = s_W2c[jb.z * 16 + kk];
                    float v7 = s_W2c[jb.w * 16 + kk];
                    SPEC8(v0, v1, v2, v3, v4, v5, v6, v7);
                  }
                }
              }
            }
          }
        };

        // 2-deep software pipeline over the chunk's events (chunk-local only:
        // next chunk's buffers are being written concurrently — do NOT cross)
        int totA, totB; float cdA, cdB; float wA[16], wB[16];
        loadEvt(0, totA, cdA, wA);
        for (int e = 0; e < CH; e += 2) {
          loadEvt(e + 1, totB, cdB, wB);        // e+1 <= 31 always (CH even)
          procEvt(e, totA, cdA, wA);
          if (e + 2 < CH) loadEvt(e + 2, totA, cdA, wA);
          procEvt(e + 1, totB, cdB, wB);
        }
      }
    }
    // one barrier per iteration separates all stage hand-offs (parity audit in header)
    __syncthreads();
  }

  if (!isProd && lane < 10) out[b * 10 + lane] = __fmul_rn(cntf, 0.015625f);
}

extern "C" void kernel_launch(void* const* d_in, const int* in_sizes, int n_in,
                              void* d_out, int out_size, void* d_ws, size_t ws_size,
                              hipStream_t stream) {
  const float* ET = (const float*)d_in[0];
  const int* EP = (const int*)d_in[1];
  const float* W1 = (const float*)d_in[2];
  const float* b1 = (const float*)d_in[3];
  const float* W2 = (const float*)d_in[4];
  const float* b2 = (const float*)d_in[5];
  float* out = (float*)d_out;

  const size_t need = (size_t)(DIN * DH + 64) * sizeof(float);
  if (ws_size >= need) {
    float* W1T = (float*)d_ws;
    hipLaunchKernelGGL(prep_transpose, dim3((DIN * DH + 64 + 255) / 256), dim3(256), 0, stream,
                       W1, W1T);
    hipLaunchKernelGGL((snn_main<true>), dim3(256), dim3(512), 0, stream,
                       ET, EP, W1T, b1, W2, b2, out);
  } else {
    // fallback: gather directly from W1 (uncoalesced but correct)
    hipLaunchKernelGGL((snn_main<false>), dim3(256), dim3(512), 0, stream,
                       ET, EP, W1, b1, W2, b2, out);
  }
}

// Round 8
// 244.709 us; speedup vs baseline: 7.8216x; 1.0354x over previous
//
#include <hip/hip_runtime.h>

#define CH 32        // events per chunk
#define NCHUNK 32    // 1024 / CH
#define NE 1024
#define DH 400
#define DIN 784
#define PF 8         // W1-row prefetch depth

// TAU = -1/ln(0.2) as the reference's Python double, rounded to f32
#define TAUF ((float)0.6213349345596119)

__global__ void prep_transpose(const float* __restrict__ W1, float* __restrict__ W1T) {
  int idx = blockIdx.x * 256 + threadIdx.x;
  const int total = DIN * DH;
  if (idx < total) {
    int p = idx / DH;
    int j = idx - p * DH;
    W1T[idx] = W1[j * DIN + p];
  } else if (idx < total + 64) {
    W1T[idx] = 0.0f;
  }
}

#define STEP(WV)                                   \
  do {                                             \
    float mn_ = __fadd_rn(h2, (WV));               \
    bool f_ = (mn_ >= 0.5f);                       \
    cntf = f_ ? (cntf + 1.0f) : cntf;              \
    h2 = f_ ? 0.0f : mn_;                          \
  } while (0)

#define SPEC8(W0, W1, W2, W3, W4, W5, W6, W7)                                  \
  do {                                                                         \
    float q0f = __fadd_rn(h2, (W0));                                           \
    float q1f = __fadd_rn(q0f, (W1));                                          \
    float q2f = __fadd_rn(q1f, (W2));                                          \
    float q3f = __fadd_rn(q2f, (W3));                                          \
    float q4f = __fadd_rn(q3f, (W4));                                          \
    float q5f = __fadd_rn(q4f, (W5));                                          \
    float q6f = __fadd_rn(q5f, (W6));                                          \
    float q7f = __fadd_rn(q6f, (W7));                                          \
    bool anyF = (q0f >= 0.5f) | (q1f >= 0.5f) | (q2f >= 0.5f) | (q3f >= 0.5f) |\
                (q4f >= 0.5f) | (q5f >= 0.5f) | (q6f >= 0.5f) | (q7f >= 0.5f); \
    if (!anyF) {                                                               \
      h2 = q7f;                                                                \
    } else {                                                                   \
      STEP(W0); STEP(W1); STEP(W2); STEP(W3);                                  \
      STEP(W4); STEP(W5); STEP(W6); STEP(W7);                                  \
    }                                                                          \
  } while (0)

#define WSEL(PW, CW, WB)                            \
  do {                                              \
    bool c_ = (N >= (PW));                          \
    q = c_ ? (CW) : q;                              \
    r = c_ ? (N - (PW)) : r;                        \
    wb = c_ ? (WB) : wb;                            \
  } while (0)

#define RSEL64()                                                               \
  unsigned lo = (unsigned)q, hi = (unsigned)(q >> 32);                         \
  unsigned pc = (unsigned)__popc(lo);                                          \
  bool gg = r >= pc; unsigned base = gg ? 32u : 0u;                            \
  unsigned x = gg ? hi : lo; r = gg ? r - pc : r;                              \
  pc = (unsigned)__popc(x & 0xFFFFu); gg = r >= pc; base += gg ? 16u : 0u;     \
  x = gg ? (x >> 16) : (x & 0xFFFFu); r = gg ? r - pc : r;                     \
  pc = (unsigned)__popc(x & 0xFFu); gg = r >= pc; base += gg ? 8u : 0u;        \
  x = gg ? (x >> 8) : (x & 0xFFu); r = gg ? r - pc : r;                        \
  pc = (unsigned)__popc(x & 0xFu); gg = r >= pc; base += gg ? 4u : 0u;         \
  x = gg ? (x >> 4) : (x & 0xFu); r = gg ? r - pc : r;                         \
  pc = (unsigned)__popc(x & 0x3u); gg = r >= pc; base += gg ? 2u : 0u;         \
  x = gg ? (x >> 2) : (x & 0x3u); r = gg ? r - pc : r;                         \
  gg = r >= (x & 1u); base += gg ? 1u : 0u;

__device__ __forceinline__ float rl_f(float v, int l) {
  return __int_as_float(__builtin_amdgcn_readlane(__float_as_int(v), l));
}

template <bool TR>
__global__ __launch_bounds__(512, 2) void snn_main(
    const float* __restrict__ ET, const int* __restrict__ EP,
    const float* __restrict__ W1x, const float* __restrict__ b1,
    const float* __restrict__ W2, const float* __restrict__ b2,
    float* __restrict__ out) {
  __shared__ float s_W2c[401 * 16];                        // W2.T + b2/400; row 400 = zeros
  __shared__ __align__(16) unsigned long long s_masksT[3][8][CH + 2];  // [buf][wave][event]
  __shared__ float s_dec1[NE];
  __shared__ float s_dec2[NE];
  __shared__ int s_EP[NE];
  __shared__ __align__(16) int s_spklist[2][CH][64];       // ordered spike lists
  __shared__ __align__(16) float s_wlistT[2][CH][16 * 20]; // [comp*20 + slot], 16 slots
  __shared__ int s_spkcnt[2][CH];
  __shared__ __align__(16) int s_spk2[64];

  const int tid = threadIdx.x;
  const int b = blockIdx.x;
  const int eb = b * NE;

  for (int i = tid; i < 401 * 16; i += 512) {
    int row = i >> 4, col = i & 15;
    float v = 0.0f;
    if (row < DH && col < 10) v = __fadd_rn(W2[col * DH + row], __fdiv_rn(b2[col], 400.0f));
    s_W2c[i] = v;
  }
  for (int i = tid; i < NE; i += 512) {
    s_EP[i] = EP[eb + i];
    float t = ET[eb + i];
    float tp = (i > 0) ? ET[eb + i - 1] : 0.0f;
    s_dec1[i] = expf(__fdiv_rn(-(t - tp), TAUF));
    float th = __fadd_rn(t, 0.1f);
    float thp = (i > 0) ? __fadd_rn(tp, 0.1f) : 0.0f;
    s_dec2[i] = expf(__fdiv_rn(-(th - thp), TAUF));
  }

  const bool isProd = (tid < 448);
  const int lane = tid & 63;
  const int wv = tid >> 6;
  const bool act = (tid < DH);

  float m1 = 0.0f;
  float b1v = act ? __fdiv_rn(b1[tid < DH ? tid : DH - 1], 784.0f) : 0.0f;
  float wp[PF];

  float h2 = 0.0f, cntf = 0.0f;
  const int kk = lane & 15;

  __syncthreads();

  if (isProd) {
#pragma unroll
    for (int i = 0; i < PF; ++i) {
      int p = s_EP[i];
      wp[i] = TR ? W1x[p * DH + tid] : W1x[(tid < DH ? tid : DH - 1) * DIN + p];
    }
  } else {
#pragma unroll
    for (int i = 0; i < PF; ++i) wp[i] = 0.0f;
  }

  // 3-stage pipeline: produce chunk it | extract chunk it-1 | consume chunk it-2
  for (int it = 0; it <= NCHUNK + 1; ++it) {
    if (isProd) {
      // ---- stage 1: masks for chunk it ----
      if (it < NCHUNK) {
        const int mb = it % 3;
        const int gbase = it * CH;
        // per-chunk lane-spread caches (2 DS ops replace 64 uniform reads)
        float decv = s_dec1[(gbase + lane) & (NE - 1)];
        int epv = s_EP[(gbase + 8 + lane) & (NE - 1)];
        unsigned long long balPrev = 0ull;
#pragma unroll
        for (int e = 0; e < CH; ++e) {
          float dv = rl_f(decv, e);                     // dec1[gbase+e] via readlane
          float mm = __fmul_rn(m1, dv);                 // exact ref order, no FMA
          mm = __fadd_rn(mm, wp[e & (PF - 1)]);
          mm = __fadd_rn(mm, b1v);
          bool fired = act && (mm >= 0.5f);
          unsigned long long bal = __ballot(fired);
          m1 = fired ? 0.0f : mm;
          if ((e & 1) == 0) {
            balPrev = bal;
          } else if (lane == 0) {                       // paired b128 write (2 events)
            ulonglong2 pr; pr.x = balPrev; pr.y = bal;
            *reinterpret_cast<ulonglong2*>(&s_masksT[mb][wv][e - 1]) = pr;
          }
          int pn = __builtin_amdgcn_readlane(epv, e);   // EP[gbase+e+8]
          wp[e & (PF - 1)] =
              TR ? W1x[pn * DH + tid] : W1x[(tid < DH ? tid : DH - 1) * DIN + pn];
        }
      }
      // ---- stage 2: extract chunk it-1 (7 waves share 32 events) ----
      if (it >= 1 && it <= NCHUNK) {
        const int c = it - 1;
        const int mb = c % 3;
        const int lb = c & 1;
        for (int e = wv; e < CH; e += 7) {
          // one lane-spread b64 read gets all 7 mask words; readlane -> uniform
          uint2 mw = *reinterpret_cast<const uint2*>(&s_masksT[mb][lane & 7][e]);
          unsigned long long c0 =
              ((unsigned long long)(unsigned)__builtin_amdgcn_readlane(mw.y, 0) << 32) |
              (unsigned)__builtin_amdgcn_readlane(mw.x, 0);
          unsigned long long c1 =
              ((unsigned long long)(unsigned)__builtin_amdgcn_readlane(mw.y, 1) << 32) |
              (unsigned)__builtin_amdgcn_readlane(mw.x, 1);
          unsigned long long c2 =
              ((unsigned long long)(unsigned)__builtin_amdgcn_readlane(mw.y, 2) << 32) |
              (unsigned)__builtin_amdgcn_readlane(mw.x, 2);
          unsigned long long c3 =
              ((unsigned long long)(unsigned)__builtin_amdgcn_readlane(mw.y, 3) << 32) |
              (unsigned)__builtin_amdgcn_readlane(mw.x, 3);
          unsigned long long c4 =
              ((unsigned long long)(unsigned)__builtin_amdgcn_readlane(mw.y, 4) << 32) |
              (unsigned)__builtin_amdgcn_readlane(mw.x, 4);
          unsigned long long c5 =
              ((unsigned long long)(unsigned)__builtin_amdgcn_readlane(mw.y, 5) << 32) |
              (unsigned)__builtin_amdgcn_readlane(mw.x, 5);
          unsigned long long c6 =
              ((unsigned long long)(unsigned)__builtin_amdgcn_readlane(mw.y, 6) << 32) |
              (unsigned)__builtin_amdgcn_readlane(mw.x, 6);
          unsigned P1 = (unsigned)__popcll(c0);
          unsigned P2 = P1 + (unsigned)__popcll(c1);
          unsigned P3 = P2 + (unsigned)__popcll(c2);
          unsigned P4 = P3 + (unsigned)__popcll(c3);
          unsigned P5 = P4 + (unsigned)__popcll(c4);
          unsigned P6 = P5 + (unsigned)__popcll(c5);
          unsigned total = P6 + (unsigned)__popcll(c6);
          unsigned N = (unsigned)lane;
          unsigned long long q = c0;
          unsigned r = N, wb = 0;
          WSEL(P1, c1, 64);  WSEL(P2, c2, 128); WSEL(P3, c3, 192);
          WSEL(P4, c4, 256); WSEL(P5, c5, 320); WSEL(P6, c6, 384);
          RSEL64();
          int j = (int)(wb + base);
          j = (N < total) ? j : DH;                     // dummy zero-weight row
          s_spklist[lb][e][lane] = j;
          if (lane == 0) s_spkcnt[lb][e] = (int)total;
          // pre-gather: slots 0..7 always; 8..15 only if needed (uniform branch)
#pragma unroll
          for (int p = 0; p < 2; ++p) {
            int sl = p * 4 + (lane >> 4);
            int js = __builtin_amdgcn_ds_bpermute(sl << 2, j);
            float w = s_W2c[js * 16 + (lane & 15)];
            s_wlistT[lb][e][(lane & 15) * 20 + sl] = w;
          }
          if (total > 8) {
#pragma unroll
            for (int p = 2; p < 4; ++p) {
              int sl = p * 4 + (lane >> 4);
              int js = __builtin_amdgcn_ds_bpermute(sl << 2, j);
              float w = s_W2c[js * 16 + (lane & 15)];
              s_wlistT[lb][e][(lane & 15) * 20 + sl] = w;
            }
          }
        }
      }
    } else {
      // ---- stage 3: consume chunk it-2 ----
      if (it >= 2) {
        const int c = it - 2;
        const int lb = c & 1;
        const int mb = c % 3;
        const int gb2 = c * CH;
        // per-chunk lane-spread caches: counts + dec2 (2 DS ops for whole chunk)
        int cntv = s_spkcnt[lb][lane & 31];
        float d2v = s_dec2[gb2 + (lane & 31)];

        auto loadEvt = [&](int ee, int& tot, float& cdv, float (&w)[16]) {
          tot = __builtin_amdgcn_readlane(cntv, ee);
          cdv = rl_f(d2v, ee);
          const float4* wrow = reinterpret_cast<const float4*>(&s_wlistT[lb][ee][kk * 20]);
          float4 a = wrow[0], b4 = wrow[1];
          w[0] = a.x; w[1] = a.y; w[2] = a.z; w[3] = a.w;
          w[4] = b4.x; w[5] = b4.y; w[6] = b4.z; w[7] = b4.w;
          if (tot > 8) {
            float4 c4 = wrow[2], d4 = wrow[3];
            w[8] = c4.x; w[9] = c4.y; w[10] = c4.z; w[11] = c4.w;
            w[12] = d4.x; w[13] = d4.y; w[14] = d4.z; w[15] = d4.w;
          }
        };
        auto procEvt = [&](int e, int tot, float cdv, float (&w)[16]) {
          h2 = __fmul_rn(h2, cdv);
          if (tot > 0) {
            SPEC8(w[0], w[1], w[2], w[3], w[4], w[5], w[6], w[7]);
            if (tot > 8) {
              SPEC8(w[8], w[9], w[10], w[11], w[12], w[13], w[14], w[15]);
            }
            if (tot > 16) {  // cold: remaining spikes from the list
              int lim = tot < 64 ? tot : 64;
              for (int dn = 16; dn < lim; dn += 8) {
                const int4* sp = (const int4*)(&s_spklist[lb][e][dn]);
                int4 ja = sp[0], jb = sp[1];
                float v0 = s_W2c[ja.x * 16 + kk];
                float v1 = s_W2c[ja.y * 16 + kk];
                float v2 = s_W2c[ja.z * 16 + kk];
                float v3 = s_W2c[ja.w * 16 + kk];
                float v4 = s_W2c[jb.x * 16 + kk];
                float v5 = s_W2c[jb.y * 16 + kk];
                float v6 = s_W2c[jb.z * 16 + kk];
                float v7 = s_W2c[jb.w * 16 + kk];
                SPEC8(v0, v1, v2, v3, v4, v5, v6, v7);
              }
              if (tot > 64) {  // colder: re-extract from still-live masks
                uint2 mw = *reinterpret_cast<const uint2*>(&s_masksT[mb][lane & 7][e]);
                unsigned long long c0 =
                    ((unsigned long long)(unsigned)__builtin_amdgcn_readlane(mw.y, 0) << 32) |
                    (unsigned)__builtin_amdgcn_readlane(mw.x, 0);
                unsigned long long c1 =
                    ((unsigned long long)(unsigned)__builtin_amdgcn_readlane(mw.y, 1) << 32) |
                    (unsigned)__builtin_amdgcn_readlane(mw.x, 1);
                unsigned long long c2 =
                    ((unsigned long long)(unsigned)__builtin_amdgcn_readlane(mw.y, 2) << 32) |
                    (unsigned)__builtin_amdgcn_readlane(mw.x, 2);
                unsigned long long c3 =
                    ((unsigned long long)(unsigned)__builtin_amdgcn_readlane(mw.y, 3) << 32) |
                    (unsigned)__builtin_amdgcn_readlane(mw.x, 3);
                unsigned long long c4 =
                    ((unsigned long long)(unsigned)__builtin_amdgcn_readlane(mw.y, 4) << 32) |
                    (unsigned)__builtin_amdgcn_readlane(mw.x, 4);
                unsigned long long c5 =
                    ((unsigned long long)(unsigned)__builtin_amdgcn_readlane(mw.y, 5) << 32) |
                    (unsigned)__builtin_amdgcn_readlane(mw.x, 5);
                unsigned long long c6 =
                    ((unsigned long long)(unsigned)__builtin_amdgcn_readlane(mw.y, 6) << 32) |
                    (unsigned)__builtin_amdgcn_readlane(mw.x, 6);
                unsigned P1 = (unsigned)__popcll(c0);
                unsigned P2 = P1 + (unsigned)__popcll(c1);
                unsigned P3 = P2 + (unsigned)__popcll(c2);
                unsigned P4 = P3 + (unsigned)__popcll(c3);
                unsigned P5 = P4 + (unsigned)__popcll(c4);
                unsigned P6 = P5 + (unsigned)__popcll(c5);
                for (int done = 64; done < tot; done += 64) {
                  unsigned N = (unsigned)(done + lane);
                  unsigned long long q = c0;
                  unsigned r = N, wb = 0;
                  WSEL(P1, c1, 64);  WSEL(P2, c2, 128); WSEL(P3, c3, 192);
                  WSEL(P4, c4, 256); WSEL(P5, c5, 320); WSEL(P6, c6, 384);
                  RSEL64();
                  int j = (int)(wb + base);
                  j = (N < (unsigned)tot) ? j : DH;
                  s_spk2[lane] = j;
                  int cnt = tot - done; cnt = cnt > 64 ? 64 : cnt;
                  int nb2 = (cnt + 7) >> 3;
                  for (int bb = 0; bb < nb2; ++bb) {
                    const int4* sp = (const int4*)(s_spk2 + bb * 8);
                    int4 ja = sp[0], jb = sp[1];
                    float v0 = s_W2c[ja.x * 16 + kk];
                    float v1 = s_W2c[ja.y * 16 + kk];
                    float v2 = s_W2c[ja.z * 16 + kk];
                    float v3 = s_W2c[ja.w * 16 + kk];
                    float v4 = s_W2c[jb.x * 16 + kk];
                    float v5 = s_W2c[jb.y * 16 + kk];
                    float v6 = s_W2c[jb.z * 16 + kk];
                    float v7 = s_W2c[jb.w * 16 + kk];
                    SPEC8(v0, v1, v2, v3, v4, v5, v6, v7);
                  }
                }
              }
            }
          }
        };

        int totA, totB; float cdA, cdB; float wA[16], wB[16];
        loadEvt(0, totA, cdA, wA);
        for (int e = 0; e < CH; e += 2) {
          loadEvt(e + 1, totB, cdB, wB);
          procEvt(e, totA, cdA, wA);
          if (e + 2 < CH) loadEvt(e + 2, totA, cdA, wA);
          procEvt(e + 1, totB, cdB, wB);
        }
      }
    }
    __syncthreads();
  }

  if (!isProd && lane < 10) out[b * 10 + lane] = __fmul_rn(cntf, 0.015625f);
}

extern "C" void kernel_launch(void* const* d_in, const int* in_sizes, int n_in,
                              void* d_out, int out_size, void* d_ws, size_t ws_size,
                              hipStream_t stream) {
  const float* ET = (const float*)d_in[0];
  const int* EP = (const int*)d_in[1];
  const float* W1 = (const float*)d_in[2];
  const float* b1 = (const float*)d_in[3];
  const float* W2 = (const float*)d_in[4];
  const float* b2 = (const float*)d_in[5];
  float* out = (float*)d_out;

  const size_t need = (size_t)(DIN * DH + 64) * sizeof(float);
  if (ws_size >= need) {
    float* W1T = (float*)d_ws;
    hipLaunchKernelGGL(prep_transpose, dim3((DIN * DH + 64 + 255) / 256), dim3(256), 0, stream,
                       W1, W1T);
    hipLaunchKernelGGL((snn_main<true>), dim3(256), dim3(512), 0, stream,
                       ET, EP, W1T, b1, W2, b2, out);
  } else {
    hipLaunchKernelGGL((snn_main<false>), dim3(256), dim3(512), 0, stream,
                       ET, EP, W1, b1, W2, b2, out);
  }
}